// Round 3
// baseline (196.063 us; speedup 1.0000x reference)
//
#include <hip/hip_runtime.h>

#define I_DIM 17
#define H_DIM 128
#define T_DIM 19
#define B_DIM 32768
#define M_ROWS 16
#define TILES 4
#define NTHR 512
#define GRID (B_DIM / (M_ROWS * TILES)) /* 512 */
#define XI (T_DIM * I_DIM)              /* 323 */

typedef __bf16 bf16x8 __attribute__((ext_vector_type(8)));
typedef float f32x4 __attribute__((ext_vector_type(4)));

union FragU { bf16x8 v; unsigned short s[8]; uint4 u; };

// LDS: WiF 32 frags*1024 = 32768 | WoF 8*1024 = 8192 | Hl [16][256B] = 4096 | Xl [16][80B] pad = 2048
#define OFF_WOF 32768
#define OFF_H   40960
#define OFF_X   45056
#define LDS_TOT 47104

__device__ __forceinline__ unsigned short f2bf(float f) {
    union { float f; unsigned u; } x; x.f = f;
    unsigned r = x.u + 0x7fffu + ((x.u >> 16) & 1u);
    return (unsigned short)(r >> 16);
}

#define K1 1.4426950408889634f
#define K2 2.8853900817779268f

__global__ __launch_bounds__(NTHR, 4) void flowlstm(
    const float* __restrict__ x, const float* __restrict__ W_ih,
    const float* __restrict__ W_hh, const float* __restrict__ b_ih,
    const float* __restrict__ b_hh, const float* __restrict__ W_out,
    const float* __restrict__ b_out, float* __restrict__ out)
{
    __shared__ __align__(16) unsigned char smem[LDS_TOT];
    const int tid = threadIdx.x;
    const int w = tid >> 6, lane = tid & 63, l15 = lane & 15, q = lane >> 4;
    const int wg = w & 3, half = w >> 2;   // wave owns gate cols g*128 + wg*32 + half*16 + l15

    // ---- stage W_ih fragments (32 frags, K padded 17->32) ----
    #pragma unroll
    for (int i = 0; i < 4; ++i) {
        int s = tid + i * NTHR;
        int ln = s & 63, f = s >> 6;
        int g = f & 3, hf = (f >> 2) & 1, wgs = f >> 3;
        int n = g * H_DIM + wgs * 32 + hf * 16 + (ln & 15);
        int kb = (ln >> 4) * 8;
        FragU fu;
        #pragma unroll
        for (int e = 0; e < 8; ++e)
            fu.s[e] = (kb + e < I_DIM) ? f2bf(W_ih[n * I_DIM + kb + e]) : (unsigned short)0;
        *(uint4*)(smem + f * 1024 + ln * 16) = fu.u;
    }
    // ---- stage W_out fragments (8 frags, N padded 17->32) ----
    {
        int ln = tid & 63, f = tid >> 6;
        int kk = f & 3, nt = f >> 2;
        int o = nt * 16 + (ln & 15);
        int kb = kk * 32 + (ln >> 4) * 8;
        FragU fu;
        #pragma unroll
        for (int e = 0; e < 8; ++e)
            fu.s[e] = (o < I_DIM) ? f2bf(W_out[o * H_DIM + kb + e]) : (unsigned short)0;
        *(uint4*)(smem + OFF_WOF + f * 1024 + ln * 16) = fu.u;
    }
    // ---- zero Xl (covers K-pad 17..31, stays zero) ----
    ((unsigned*)(smem + OFF_X))[tid] = 0u;

    // ---- W_hh fragments in REGISTERS: 16 frags = 64 VGPR ----
    bf16x8 whh[4][4];
    #pragma unroll
    for (int kk = 0; kk < 4; ++kk)
        #pragma unroll
        for (int g = 0; g < 4; ++g) {
            int n = g * H_DIM + wg * 32 + half * 16 + l15;
            const float* s = W_hh + n * H_DIM + kk * 32 + q * 8;
            FragU fu;
            #pragma unroll
            for (int e = 0; e < 8; ++e) fu.s[e] = f2bf(s[e]);
            whh[kk][g] = fu.v;
        }
    float bias[4];
    #pragma unroll
    for (int g = 0; g < 4; ++g) {
        int col = g * H_DIM + wg * 32 + half * 16 + l15;
        bias[g] = b_ih[col] + b_hh[col];
    }
    // ---- t-invariant LDS offsets ----
    const unsigned xr7 = (unsigned)((l15 & 7) << 4);
    unsigned aoff[4], woff[4];
    #pragma unroll
    for (int kk = 0; kk < 4; ++kk)
        aoff[kk] = (unsigned)(OFF_H + l15 * 256 + (((kk * 64) | (q * 16)) ^ xr7));
    #pragma unroll
    for (int r = 0; r < 4; ++r) {
        int row = q * 4 + r;
        woff[r] = (unsigned)(OFF_H + row * 256 +
                             (((wg * 32 + half * 16 + l15) * 2) ^ ((row & 7) << 4)));
    }
    const unsigned xaoff = (unsigned)(OFF_X + l15 * 80 + q * 16);
    const unsigned wifb  = (unsigned)(((wg * 2 + half) * 4) * 1024 + lane * 16);
    const float ybo = (w == 0) ? b_out[l15] : b_out[16];

    const bool xv = tid < M_ROWS * I_DIM;              // 272 stagers
    const int xrow = tid / I_DIM;
    const int xk = tid - xrow * I_DIM;
    const unsigned xlo = (unsigned)(OFF_X + xrow * 80 + xk * 2);

    __syncthreads();   // prologue staging + Xl zero visible

    #pragma unroll 1
    for (int tile = 0; tile < TILES; ++tile) {
        const int b0 = blockIdx.x * (M_ROWS * TILES) + tile * M_ROWS;
        const float* xp = x + (size_t)(b0 + xrow) * XI + xk;
        float cst[4] = {0.f, 0.f, 0.f, 0.f};
        if (xv) *(unsigned short*)(smem + xlo) = f2bf(xp[0]);
        __syncthreads();
        float xr1 = 0.f;
        #pragma unroll 1
        for (int t = 0; t < T_DIM; ++t) {
            if (xv && t + 1 < T_DIM) xr1 = xp[(size_t)(t + 1) * I_DIM];  // prefetch
            // ---- y_{t-1} = h_{t-1} @ W_out^T (waves 0,1) ----
            if (t > 0 && w < 2) {
                f32x4 ya = {0.f, 0.f, 0.f, 0.f};
                #pragma unroll
                for (int kk = 0; kk < 4; ++kk) {
                    bf16x8 a = *(const bf16x8*)(smem + aoff[kk]);
                    bf16x8 b = *(const bf16x8*)(smem + OFF_WOF + (w * 4 + kk) * 1024 + lane * 16);
                    ya = __builtin_amdgcn_mfma_f32_16x16x32_bf16(a, b, ya, 0, 0, 0);
                }
                int col = w * 16 + l15;
                if (col < I_DIM) {
                    #pragma unroll
                    for (int r = 0; r < 4; ++r)
                        out[((size_t)(b0 + q * 4 + r) * T_DIM + (t - 1)) * I_DIM + col] = ya[r] + ybo;
                }
            }
            // ---- gates = bias + x_t@W_ih^T (+ h_{t-1}@W_hh^T for t>0) ----
            f32x4 acc[4];
            #pragma unroll
            for (int g = 0; g < 4; ++g) acc[g] = (f32x4){bias[g], bias[g], bias[g], bias[g]};
            {
                bf16x8 a = *(const bf16x8*)(smem + xaoff);
                #pragma unroll
                for (int g = 0; g < 4; ++g) {
                    bf16x8 b = *(const bf16x8*)(smem + wifb + g * 1024);
                    acc[g] = __builtin_amdgcn_mfma_f32_16x16x32_bf16(a, b, acc[g], 0, 0, 0);
                }
            }
            if (t > 0) {
                #pragma unroll
                for (int kk = 0; kk < 4; ++kk) {
                    bf16x8 a = *(const bf16x8*)(smem + aoff[kk]);
                    #pragma unroll
                    for (int g = 0; g < 4; ++g)
                        acc[g] = __builtin_amdgcn_mfma_f32_16x16x32_bf16(a, whh[kk][g], acc[g], 0, 0, 0);
                }
            }
            // ---- elementwise: 5 exp2 + 2 rcp per cell ----
            unsigned short hs[4];
            #pragma unroll
            for (int r = 0; r < 4; ++r) {
                float ig = acc[0][r], fg = acc[1][r], gg = acc[2][r], og = acc[3][r];
                float ui = __builtin_amdgcn_exp2f(-K1 * ig);
                float uf = __builtin_amdgcn_exp2f(-K1 * fg);
                float vg = __builtin_amdgcn_exp2f(-K2 * gg);
                float uo = __builtin_amdgcn_exp2f(-K1 * og);
                float A = 1.f + ui, F = 1.f + uf, G = 1.f + vg;
                float AG = A * G;
                float num = cst[r] * AG + (1.f - vg) * F;
                float c = num * __builtin_amdgcn_rcpf(F * AG);
                cst[r] = c;
                float vc = __builtin_amdgcn_exp2f(-K2 * c);
                float h = (1.f - vc) * __builtin_amdgcn_rcpf((1.f + uo) * (1.f + vc));
                hs[r] = f2bf(h);
            }
            __syncthreads();   // all reads of Hl/Xl done
            #pragma unroll
            for (int r = 0; r < 4; ++r)
                *(unsigned short*)(smem + woff[r]) = hs[r];
            if (xv && t + 1 < T_DIM) *(unsigned short*)(smem + xlo) = f2bf(xr1);
            __syncthreads();   // h_t / x_{t+1} visible
        }
        // ---- epilogue: y_{T-1} ----
        if (w < 2) {
            f32x4 ya = {0.f, 0.f, 0.f, 0.f};
            #pragma unroll
            for (int kk = 0; kk < 4; ++kk) {
                bf16x8 a = *(const bf16x8*)(smem + aoff[kk]);
                bf16x8 b = *(const bf16x8*)(smem + OFF_WOF + (w * 4 + kk) * 1024 + lane * 16);
                ya = __builtin_amdgcn_mfma_f32_16x16x32_bf16(a, b, ya, 0, 0, 0);
            }
            int col = w * 16 + l15;
            if (col < I_DIM) {
                #pragma unroll
                for (int r = 0; r < 4; ++r)
                    out[((size_t)(b0 + q * 4 + r) * T_DIM + (T_DIM - 1)) * I_DIM + col] = ya[r] + ybo;
            }
        }
        // next tile's first Hl write is after its own in-loop barrier; no extra sync needed
    }
}

extern "C" void kernel_launch(void* const* d_in, const int* in_sizes, int n_in,
                              void* d_out, int out_size, void* d_ws, size_t ws_size,
                              hipStream_t stream) {
    const float* x     = (const float*)d_in[0];
    const float* W_ih  = (const float*)d_in[1];
    const float* W_hh  = (const float*)d_in[2];
    const float* b_ih  = (const float*)d_in[3];
    const float* b_hh  = (const float*)d_in[4];
    const float* W_out = (const float*)d_in[5];
    const float* b_out = (const float*)d_in[6];
    float* out = (float*)d_out;

    dim3 grid(GRID), block(NTHR);
    flowlstm<<<grid, block, 0, stream>>>(x, W_ih, W_hh, b_ih, b_hh, W_out, b_out, out);
}